// Round 8
// baseline (148.792 us; speedup 1.0000x reference)
//
#include <hip/hip_runtime.h>

// TensorProductConv: Z[rows[e]] += msg(X[cols[e]], Y[e], W[e]),  msg is 352 f32.
// Inputs: X (N,128) f32, Y (E,4) f32, W (E,160) f32, rows (E) int32, cols (E) int32
// Output: Z (N, 352) f32.
//
// Build: fixed-capacity binning, KCAP=64, slots hold edge id only (int) ->
// 12.8 MB bin array (L2-resident). memset(cnt) + scatter_bin. Overflow edges
// (never in practice; Poisson(10) degrees) go to a list handled by an atomic
// cleanup pass after the gather.
// Gather: one 32-lane half-wave per node; cols[e]/Y[e] read through cache
// (R4/R5: indirection is free); accumulate in registers; write Z once.

#define SQRT3_INV 0.57735026918962576451f
#define SQRT2_INV 0.70710678118654752440f
#define KCAP 64

// ---------- build: bin edges by destination row ----------
__global__ void scatter_bin_kernel(const int* __restrict__ rows,
                                   int* __restrict__ cnt, int* __restrict__ slots,
                                   int* __restrict__ ovf_cnt, int* __restrict__ ovf_list,
                                   int nE) {
    int e = blockIdx.x * blockDim.x + threadIdx.x;
    if (e >= nE) return;
    int r = rows[e];
    int p = atomicAdd(&cnt[r], 1);
    if (p < KCAP) {
        slots[r * KCAP + p] = e;
    } else {
        int q = atomicAdd(ovf_cnt, 1);
        ovf_list[q] = e;
    }
}

// ---------- main gather: one node per 32-lane half-wave ----------
__global__ __launch_bounds__(256) void tpc_gather(
    const float* __restrict__ X,
    const float* __restrict__ Y,
    const float* __restrict__ W,
    const int* __restrict__ cols,
    const int* __restrict__ slots,
    const int* __restrict__ cnt,
    float* __restrict__ Z,
    int n_nodes)
{
    int node = blockIdx.x * 8 + (threadIdx.x >> 5);   // 8 half-waves per 256-thr block
    if (node >= n_nodes) return;
    int u = threadIdx.x & 31;

    float a1 = 0.f, a2a = 0.f, a2b = 0.f, a2c = 0.f;
    float a3a = 0.f, a3b = 0.f, a3c = 0.f, a4 = 0.f;
    float a5a = 0.f, a5b = 0.f, a5c = 0.f;

    int n = cnt[node];
    if (n > KCAP) n = KCAP;
    const int* sb = slots + node * KCAP;

#define EDGE_BODY(E_, C_)                                                     \
    do {                                                                      \
        const float* We = W + (size_t)(unsigned)(E_) * 160;                   \
        const float* Xr = X + (size_t)(unsigned)(C_) * 128;                   \
        const float* Ye = Y + (size_t)(unsigned)(E_) * 4;                     \
        const float x0  = Xr[u];                                              \
        const float x1a = Xr[32 + 3 * u + 0];                                 \
        const float x1b = Xr[32 + 3 * u + 1];                                 \
        const float x1c = Xr[32 + 3 * u + 2];                                 \
        const float y0  = Ye[0];                                              \
        const float y1a = Ye[1];                                              \
        const float y1b = Ye[2];                                              \
        const float y1c = Ye[3];                                              \
        const float w0 = __builtin_nontemporal_load(We + u);                  \
        const float w1 = __builtin_nontemporal_load(We + 32 + u);             \
        const float w2 = __builtin_nontemporal_load(We + 64 + u);             \
        const float w3 = __builtin_nontemporal_load(We + 96 + u);             \
        const float w4 = __builtin_nontemporal_load(We + 128 + u);            \
        a1 += w0 * x0 * y0;                                                   \
        const float w1x0 = w1 * x0;                                           \
        a2a += w1x0 * y1a; a2b += w1x0 * y1b; a2c += w1x0 * y1c;              \
        const float w2y0 = w2 * y0;                                           \
        a3a += w2y0 * x1a; a3b += w2y0 * x1b; a3c += w2y0 * x1c;              \
        const float dot = x1a * y1a + x1b * y1b + x1c * y1c;                  \
        a4 += w3 * dot * SQRT3_INV;                                           \
        const float w4s = w4 * SQRT2_INV;                                     \
        a5a += w4s * (x1b * y1c - x1c * y1b);                                 \
        a5b += w4s * (x1c * y1a - x1a * y1c);                                 \
        a5c += w4s * (x1a * y1b - x1b * y1a);                                 \
    } while (0)

    int i = 0;
    for (; i + 1 < n; i += 2) {
        const int e0 = sb[i];
        const int e1 = sb[i + 1];
        const int c0 = cols[e0];
        const int c1 = cols[e1];
        EDGE_BODY(e0, c0);
        EDGE_BODY(e1, c1);
    }
    if (i < n) {
        const int e0 = sb[i];
        const int c0 = cols[e0];
        EDGE_BODY(e0, c0);
    }
#undef EDGE_BODY

    float* Zr = Z + (size_t)node * 352;
    __builtin_nontemporal_store(a1,  Zr + u);
    __builtin_nontemporal_store(a2a, Zr + 32 + 3 * u + 0);
    __builtin_nontemporal_store(a2b, Zr + 32 + 3 * u + 1);
    __builtin_nontemporal_store(a2c, Zr + 32 + 3 * u + 2);
    __builtin_nontemporal_store(a3a, Zr + 128 + 3 * u + 0);
    __builtin_nontemporal_store(a3b, Zr + 128 + 3 * u + 1);
    __builtin_nontemporal_store(a3c, Zr + 128 + 3 * u + 2);
    __builtin_nontemporal_store(a4,  Zr + 224 + u);
    __builtin_nontemporal_store(a5a, Zr + 256 + 3 * u + 0);
    __builtin_nontemporal_store(a5b, Zr + 256 + 3 * u + 1);
    __builtin_nontemporal_store(a5c, Zr + 256 + 3 * u + 2);
}

// ---------- overflow cleanup: atomically add overflowed edges into Z ----------
__global__ void ovf_kernel(const float* __restrict__ X, const float* __restrict__ Y,
                           const float* __restrict__ W, const int* __restrict__ rows,
                           const int* __restrict__ cols, const int* __restrict__ ovf_cnt,
                           const int* __restrict__ ovf_list, float* __restrict__ Z) {
    const int total = ovf_cnt[0] * 32;
    for (int idx = blockIdx.x * blockDim.x + threadIdx.x; idx < total;
         idx += gridDim.x * blockDim.x) {
        const int e = ovf_list[idx >> 5];
        const int u = idx & 31;
        const int r = rows[e];
        const int c = cols[e];
        const float* Xr = X + (size_t)c * 128;
        const float x0 = Xr[u];
        const float x1a = Xr[32 + 3 * u], x1b = Xr[33 + 3 * u], x1c = Xr[34 + 3 * u];
        const float* Ye = Y + (size_t)e * 4;
        const float y0 = Ye[0], y1a = Ye[1], y1b = Ye[2], y1c = Ye[3];
        const float* We = W + (size_t)e * 160;
        const float w0 = We[u], w1 = We[32 + u], w2 = We[64 + u], w3 = We[96 + u], w4 = We[128 + u];
        const float w1x0 = w1 * x0;
        const float w2y0 = w2 * y0;
        const float dot = x1a * y1a + x1b * y1b + x1c * y1c;
        const float w4s = w4 * SQRT2_INV;
        float* Zr = Z + (size_t)r * 352;
        atomicAdd(&Zr[u], w0 * x0 * y0);
        atomicAdd(&Zr[32 + 3 * u + 0], w1x0 * y1a);
        atomicAdd(&Zr[32 + 3 * u + 1], w1x0 * y1b);
        atomicAdd(&Zr[32 + 3 * u + 2], w1x0 * y1c);
        atomicAdd(&Zr[128 + 3 * u + 0], w2y0 * x1a);
        atomicAdd(&Zr[128 + 3 * u + 1], w2y0 * x1b);
        atomicAdd(&Zr[128 + 3 * u + 2], w2y0 * x1c);
        atomicAdd(&Zr[224 + u], w3 * dot * SQRT3_INV);
        atomicAdd(&Zr[256 + 3 * u + 0], w4s * (x1b * y1c - x1c * y1b));
        atomicAdd(&Zr[256 + 3 * u + 1], w4s * (x1c * y1a - x1a * y1c));
        atomicAdd(&Zr[256 + 3 * u + 2], w4s * (x1a * y1b - x1b * y1a));
    }
}

// ---------- fallback (atomic version) if workspace is too small ----------
__global__ __launch_bounds__(256) void tpc_edge_kernel(
    const float* __restrict__ X, const float* __restrict__ Y, const float* __restrict__ W,
    const int* __restrict__ rows, const int* __restrict__ cols, float* __restrict__ Z, int n_edges)
{
    int gid = blockIdx.x * blockDim.x + threadIdx.x;
    int e = gid >> 5;
    int u = gid & 31;
    if (e >= n_edges) return;
    const int r = rows[e];
    const int c = cols[e];
    const float* Xr = X + (size_t)c * 128;
    const float x0 = Xr[u];
    const float x1a = Xr[32 + 3 * u], x1b = Xr[33 + 3 * u], x1c = Xr[34 + 3 * u];
    const float* Ye = Y + (size_t)e * 4;
    const float y0 = Ye[0], y1a = Ye[1], y1b = Ye[2], y1c = Ye[3];
    const float* We = W + (size_t)e * 160;
    const float w0 = We[u], w1 = We[32 + u], w2 = We[64 + u], w3 = We[96 + u], w4 = We[128 + u];
    const float w1x0 = w1 * x0;
    const float w2y0 = w2 * y0;
    const float dot = x1a * y1a + x1b * y1b + x1c * y1c;
    const float w4s = w4 * SQRT2_INV;
    float* Zr = Z + (size_t)r * 352;
    atomicAdd(&Zr[u], w0 * x0 * y0);
    atomicAdd(&Zr[32 + 3 * u + 0], w1x0 * y1a);
    atomicAdd(&Zr[32 + 3 * u + 1], w1x0 * y1b);
    atomicAdd(&Zr[32 + 3 * u + 2], w1x0 * y1c);
    atomicAdd(&Zr[128 + 3 * u + 0], w2y0 * x1a);
    atomicAdd(&Zr[128 + 3 * u + 1], w2y0 * x1b);
    atomicAdd(&Zr[128 + 3 * u + 2], w2y0 * x1c);
    atomicAdd(&Zr[224 + u], w3 * dot * SQRT3_INV);
    atomicAdd(&Zr[256 + 3 * u + 0], w4s * (x1b * y1c - x1c * y1b));
    atomicAdd(&Zr[256 + 3 * u + 1], w4s * (x1c * y1a - x1a * y1c));
    atomicAdd(&Zr[256 + 3 * u + 2], w4s * (x1a * y1b - x1b * y1a));
}

extern "C" void kernel_launch(void* const* d_in, const int* in_sizes, int n_in,
                              void* d_out, int out_size, void* d_ws, size_t ws_size,
                              hipStream_t stream) {
    const float* X    = (const float*)d_in[0];
    const float* Y    = (const float*)d_in[1];
    const float* W    = (const float*)d_in[2];
    const int*   rows = (const int*)d_in[3];
    const int*   cols = (const int*)d_in[4];
    float* Z = (float*)d_out;

    const int n_edges = in_sizes[3];
    const int n_nodes = in_sizes[0] / 128;

    // ws layout: slots int[n_nodes*KCAP] | cnt[n_nodes] | ovf_cnt[1] | ovf_list[n_edges]
    size_t slots_bytes = (size_t)n_nodes * KCAP * sizeof(int);
    size_t need = slots_bytes + (size_t)(n_nodes + 1 + n_edges) * sizeof(int);
    if (ws_size < need) {
        hipMemsetAsync(d_out, 0, (size_t)out_size * sizeof(float), stream);
        const long long threads_total = (long long)n_edges * 32;
        const int grid = (int)((threads_total + 255) / 256);
        tpc_edge_kernel<<<grid, 256, 0, stream>>>(X, Y, W, rows, cols, Z, n_edges);
        return;
    }

    char* base = (char*)d_ws;
    int* slots   = (int*)base;
    int* cnt     = (int*)(base + slots_bytes);
    int* ovf_cnt = cnt + n_nodes;
    int* ovf_list= ovf_cnt + 1;

    // zero cnt + ovf_cnt in one memset
    hipMemsetAsync(cnt, 0, (size_t)(n_nodes + 1) * sizeof(int), stream);

    const int gE = (n_edges + 255) / 256;
    scatter_bin_kernel<<<gE, 256, 0, stream>>>(rows, cnt, slots, ovf_cnt, ovf_list, n_edges);

    const int gG = (n_nodes + 7) / 8;
    tpc_gather<<<gG, 256, 0, stream>>>(X, Y, W, cols, slots, cnt, Z, n_nodes);

    // overflow cleanup (normally zero work)
    ovf_kernel<<<64, 256, 0, stream>>>(X, Y, W, rows, cols, ovf_cnt, ovf_list, Z);
}

// Round 9
// 142.423 us; speedup vs baseline: 1.0447x; 1.0447x over previous
//
#include <hip/hip_runtime.h>

// TensorProductConv: Z[rows[e]] += msg(X[cols[e]], Y[e], W[e]),  msg is 352 f32.
// Inputs: X (N,128) f32, Y (E,4) f32, W (E,160) f32, rows (E) int32, cols (E) int32
// Output: Z (N, 352) f32.
//
// R7 structure (best: 142.6 us): fixed-capacity binning KCAP=128 with {e,col}
// i2 slots, memset(cnt) + scatter_bin + gather + overflow cleanup.
// R9 delta: gather loads x1 as one dwordx3 (per-lane-contiguous 12 B) instead
// of 3 strided dword gathers, and Y as one dwordx4 — fewer VMEM requests,
// same bytes.

#define SQRT3_INV 0.57735026918962576451f
#define SQRT2_INV 0.70710678118654752440f
#define KCAP 128

typedef __attribute__((ext_vector_type(4))) float f4;
typedef __attribute__((ext_vector_type(2))) int   i2;
struct F3 { float a, b, c; };   // size 12, align 4 -> global_load_dwordx3

// ---------- build: bin edges by destination row ----------
__global__ void scatter_bin_kernel(const int* __restrict__ rows, const int* __restrict__ cols,
                                   int* __restrict__ cnt, i2* __restrict__ slots,
                                   int* __restrict__ ovf_cnt, int* __restrict__ ovf_list,
                                   int nE) {
    int e = blockIdx.x * blockDim.x + threadIdx.x;
    if (e >= nE) return;
    int r = rows[e];
    int p = atomicAdd(&cnt[r], 1);
    if (p < KCAP) {
        i2 rec; rec.x = e; rec.y = cols[e];
        slots[(size_t)r * KCAP + p] = rec;
    } else {
        int q = atomicAdd(ovf_cnt, 1);
        ovf_list[q] = e;
    }
}

// ---------- main gather: one node per 32-lane half-wave ----------
__global__ __launch_bounds__(256) void tpc_gather(
    const float* __restrict__ X,
    const float* __restrict__ Y,
    const float* __restrict__ W,
    const i2* __restrict__ slots,
    const int* __restrict__ cnt,
    float* __restrict__ Z,
    int n_nodes)
{
    int node = blockIdx.x * 8 + (threadIdx.x >> 5);   // 8 half-waves per 256-thr block
    if (node >= n_nodes) return;
    int u = threadIdx.x & 31;

    float a1 = 0.f, a2a = 0.f, a2b = 0.f, a2c = 0.f;
    float a3a = 0.f, a3b = 0.f, a3c = 0.f, a4 = 0.f;
    float a5a = 0.f, a5b = 0.f, a5c = 0.f;

    int n = cnt[node];
    if (n > KCAP) n = KCAP;
    const i2* sb = slots + (size_t)node * KCAP;

#define EDGE_BODY(EC_)                                                        \
    do {                                                                      \
        const float* We = W + (size_t)(unsigned)(EC_).x * 160;                \
        const float* Xr = X + (size_t)(unsigned)(EC_).y * 128;                \
        const f4 yv = *reinterpret_cast<const f4*>(Y + (size_t)(unsigned)(EC_).x * 4); \
        const float x0 = Xr[u];                                               \
        const F3 x1 = *reinterpret_cast<const F3*>(Xr + 32 + 3 * u);          \
        const float x1a = x1.a, x1b = x1.b, x1c = x1.c;                       \
        const float y0 = yv.x, y1a = yv.y, y1b = yv.z, y1c = yv.w;            \
        const float w0 = __builtin_nontemporal_load(We + u);                  \
        const float w1 = __builtin_nontemporal_load(We + 32 + u);             \
        const float w2 = __builtin_nontemporal_load(We + 64 + u);             \
        const float w3 = __builtin_nontemporal_load(We + 96 + u);             \
        const float w4 = __builtin_nontemporal_load(We + 128 + u);            \
        a1 += w0 * x0 * y0;                                                   \
        const float w1x0 = w1 * x0;                                           \
        a2a += w1x0 * y1a; a2b += w1x0 * y1b; a2c += w1x0 * y1c;              \
        const float w2y0 = w2 * y0;                                           \
        a3a += w2y0 * x1a; a3b += w2y0 * x1b; a3c += w2y0 * x1c;              \
        const float dot = x1a * y1a + x1b * y1b + x1c * y1c;                  \
        a4 += w3 * dot * SQRT3_INV;                                           \
        const float w4s = w4 * SQRT2_INV;                                     \
        a5a += w4s * (x1b * y1c - x1c * y1b);                                 \
        a5b += w4s * (x1c * y1a - x1a * y1c);                                 \
        a5c += w4s * (x1a * y1b - x1b * y1a);                                 \
    } while (0)

    int i = 0;
    for (; i + 1 < n; i += 2) {
        const i2 ec0 = sb[i];
        const i2 ec1 = sb[i + 1];
        EDGE_BODY(ec0);
        EDGE_BODY(ec1);
    }
    if (i < n) {
        const i2 ec0 = sb[i];
        EDGE_BODY(ec0);
    }
#undef EDGE_BODY

    float* Zr = Z + (size_t)node * 352;
    __builtin_nontemporal_store(a1,  Zr + u);
    __builtin_nontemporal_store(a2a, Zr + 32 + 3 * u + 0);
    __builtin_nontemporal_store(a2b, Zr + 32 + 3 * u + 1);
    __builtin_nontemporal_store(a2c, Zr + 32 + 3 * u + 2);
    __builtin_nontemporal_store(a3a, Zr + 128 + 3 * u + 0);
    __builtin_nontemporal_store(a3b, Zr + 128 + 3 * u + 1);
    __builtin_nontemporal_store(a3c, Zr + 128 + 3 * u + 2);
    __builtin_nontemporal_store(a4,  Zr + 224 + u);
    __builtin_nontemporal_store(a5a, Zr + 256 + 3 * u + 0);
    __builtin_nontemporal_store(a5b, Zr + 256 + 3 * u + 1);
    __builtin_nontemporal_store(a5c, Zr + 256 + 3 * u + 2);
}

// ---------- overflow cleanup: atomically add overflowed edges into Z ----------
__global__ void ovf_kernel(const float* __restrict__ X, const float* __restrict__ Y,
                           const float* __restrict__ W, const int* __restrict__ rows,
                           const int* __restrict__ cols, const int* __restrict__ ovf_cnt,
                           const int* __restrict__ ovf_list, float* __restrict__ Z) {
    const int total = ovf_cnt[0] * 32;
    for (int idx = blockIdx.x * blockDim.x + threadIdx.x; idx < total;
         idx += gridDim.x * blockDim.x) {
        const int e = ovf_list[idx >> 5];
        const int u = idx & 31;
        const int r = rows[e];
        const int c = cols[e];
        const float* Xr = X + (size_t)c * 128;
        const float x0 = Xr[u];
        const float x1a = Xr[32 + 3 * u], x1b = Xr[33 + 3 * u], x1c = Xr[34 + 3 * u];
        const float* Ye = Y + (size_t)e * 4;
        const float y0 = Ye[0], y1a = Ye[1], y1b = Ye[2], y1c = Ye[3];
        const float* We = W + (size_t)e * 160;
        const float w0 = We[u], w1 = We[32 + u], w2 = We[64 + u], w3 = We[96 + u], w4 = We[128 + u];
        const float w1x0 = w1 * x0;
        const float w2y0 = w2 * y0;
        const float dot = x1a * y1a + x1b * y1b + x1c * y1c;
        const float w4s = w4 * SQRT2_INV;
        float* Zr = Z + (size_t)r * 352;
        atomicAdd(&Zr[u], w0 * x0 * y0);
        atomicAdd(&Zr[32 + 3 * u + 0], w1x0 * y1a);
        atomicAdd(&Zr[32 + 3 * u + 1], w1x0 * y1b);
        atomicAdd(&Zr[32 + 3 * u + 2], w1x0 * y1c);
        atomicAdd(&Zr[128 + 3 * u + 0], w2y0 * x1a);
        atomicAdd(&Zr[128 + 3 * u + 1], w2y0 * x1b);
        atomicAdd(&Zr[128 + 3 * u + 2], w2y0 * x1c);
        atomicAdd(&Zr[224 + u], w3 * dot * SQRT3_INV);
        atomicAdd(&Zr[256 + 3 * u + 0], w4s * (x1b * y1c - x1c * y1b));
        atomicAdd(&Zr[256 + 3 * u + 1], w4s * (x1c * y1a - x1a * y1c));
        atomicAdd(&Zr[256 + 3 * u + 2], w4s * (x1a * y1b - x1b * y1a));
    }
}

// ---------- fallback (atomic version) if workspace is too small ----------
__global__ __launch_bounds__(256) void tpc_edge_kernel(
    const float* __restrict__ X, const float* __restrict__ Y, const float* __restrict__ W,
    const int* __restrict__ rows, const int* __restrict__ cols, float* __restrict__ Z, int n_edges)
{
    int gid = blockIdx.x * blockDim.x + threadIdx.x;
    int e = gid >> 5;
    int u = gid & 31;
    if (e >= n_edges) return;
    const int r = rows[e];
    const int c = cols[e];
    const float* Xr = X + (size_t)c * 128;
    const float x0 = Xr[u];
    const float x1a = Xr[32 + 3 * u], x1b = Xr[33 + 3 * u], x1c = Xr[34 + 3 * u];
    const float* Ye = Y + (size_t)e * 4;
    const float y0 = Ye[0], y1a = Ye[1], y1b = Ye[2], y1c = Ye[3];
    const float* We = W + (size_t)e * 160;
    const float w0 = We[u], w1 = We[32 + u], w2 = We[64 + u], w3 = We[96 + u], w4 = We[128 + u];
    const float w1x0 = w1 * x0;
    const float w2y0 = w2 * y0;
    const float dot = x1a * y1a + x1b * y1b + x1c * y1c;
    const float w4s = w4 * SQRT2_INV;
    float* Zr = Z + (size_t)r * 352;
    atomicAdd(&Zr[u], w0 * x0 * y0);
    atomicAdd(&Zr[32 + 3 * u + 0], w1x0 * y1a);
    atomicAdd(&Zr[32 + 3 * u + 1], w1x0 * y1b);
    atomicAdd(&Zr[32 + 3 * u + 2], w1x0 * y1c);
    atomicAdd(&Zr[128 + 3 * u + 0], w2y0 * x1a);
    atomicAdd(&Zr[128 + 3 * u + 1], w2y0 * x1b);
    atomicAdd(&Zr[128 + 3 * u + 2], w2y0 * x1c);
    atomicAdd(&Zr[224 + u], w3 * dot * SQRT3_INV);
    atomicAdd(&Zr[256 + 3 * u + 0], w4s * (x1b * y1c - x1c * y1b));
    atomicAdd(&Zr[256 + 3 * u + 1], w4s * (x1c * y1a - x1a * y1c));
    atomicAdd(&Zr[256 + 3 * u + 2], w4s * (x1a * y1b - x1b * y1a));
}

extern "C" void kernel_launch(void* const* d_in, const int* in_sizes, int n_in,
                              void* d_out, int out_size, void* d_ws, size_t ws_size,
                              hipStream_t stream) {
    const float* X    = (const float*)d_in[0];
    const float* Y    = (const float*)d_in[1];
    const float* W    = (const float*)d_in[2];
    const int*   rows = (const int*)d_in[3];
    const int*   cols = (const int*)d_in[4];
    float* Z = (float*)d_out;

    const int n_edges = in_sizes[3];
    const int n_nodes = in_sizes[0] / 128;

    // ws layout: slots i2[n_nodes*KCAP] | cnt[n_nodes] | ovf_cnt[1] | ovf_list[n_edges]
    size_t slots_bytes = (size_t)n_nodes * KCAP * sizeof(i2);
    size_t need = slots_bytes + (size_t)(n_nodes + 1 + n_edges) * sizeof(int);
    if (ws_size < need) {
        hipMemsetAsync(d_out, 0, (size_t)out_size * sizeof(float), stream);
        const long long threads_total = (long long)n_edges * 32;
        const int grid = (int)((threads_total + 255) / 256);
        tpc_edge_kernel<<<grid, 256, 0, stream>>>(X, Y, W, rows, cols, Z, n_edges);
        return;
    }

    char* base = (char*)d_ws;
    i2*  slots   = (i2*)base;
    int* cnt     = (int*)(base + slots_bytes);
    int* ovf_cnt = cnt + n_nodes;
    int* ovf_list= ovf_cnt + 1;

    // zero cnt + ovf_cnt in one memset
    hipMemsetAsync(cnt, 0, (size_t)(n_nodes + 1) * sizeof(int), stream);

    const int gE = (n_edges + 255) / 256;
    scatter_bin_kernel<<<gE, 256, 0, stream>>>(rows, cols, cnt, slots, ovf_cnt, ovf_list, n_edges);

    const int gG = (n_nodes + 7) / 8;
    tpc_gather<<<gG, 256, 0, stream>>>(X, Y, W, slots, cnt, Z, n_nodes);

    // overflow cleanup (normally zero work)
    ovf_kernel<<<64, 256, 0, stream>>>(X, Y, W, rows, cols, ovf_cnt, ovf_list, Z);
}